// Round 1
// baseline (11764.758 us; speedup 1.0000x reference)
//
#include <hip/hip_runtime.h>

#define B_  64
#define T_  512
#define I_  256
#define H_  512
#define O_  256
#define JW  4      // j-split workgroups per group
#define BS  16     // batch rows per group (one 16-row M tile)
#define NG  (B_ / BS)  // 4 groups

typedef __attribute__((ext_vector_type(8))) __bf16 bf16x8;
typedef __attribute__((ext_vector_type(4))) float f32x4;

__device__ __forceinline__ unsigned short f2bf(float f) {
    unsigned int u = __float_as_uint(f);
    unsigned int r = (u + 0x7fffu + ((u >> 16) & 1u)) >> 16;
    return (unsigned short)r;
}

// ---------------- convert f32 -> bf16 (x4 vectorized) ----------------
__global__ void cvt_kernel(const float* __restrict__ in, unsigned short* __restrict__ out, int n4) {
    int i = blockIdx.x * blockDim.x + threadIdx.x;
    if (i >= n4) return;
    float4 f = reinterpret_cast<const float4*>(in)[i];
    ushort4 o;
    o.x = f2bf(f.x); o.y = f2bf(f.y); o.z = f2bf(f.z); o.w = f2bf(f.w);
    reinterpret_cast<ushort4*>(out)[i] = o;
}

// ---------------- generic GEMM: C[M][N] = A[M][K] @ Bw[N][K]^T + b0 + b1 ----------------
// block: 256 threads (4 waves), block tile 64M x 64N, wave tile 16M x 64N
__global__ __launch_bounds__(256) void gemm_kernel(
    const unsigned short* __restrict__ A,
    const unsigned short* __restrict__ Bw,
    const float* __restrict__ b0,
    const float* __restrict__ b1,
    float* __restrict__ C,
    int M, int N, int K)
{
    const int m0 = blockIdx.x * 64;
    const int n0 = blockIdx.y * 64;
    const int tid = threadIdx.x;
    const int wv = tid >> 6;
    const int l = tid & 63;
    const int lr = l & 15;
    const int lk = (l >> 4) * 8;
    const int arow = m0 + wv * 16 + lr;

    f32x4 acc[4] = {{0,0,0,0},{0,0,0,0},{0,0,0,0},{0,0,0,0}};
    const int nks = K / 32;
    for (int ks = 0; ks < nks; ++ks) {
        bf16x8 a = *reinterpret_cast<const bf16x8*>(A + (size_t)arow * K + ks * 32 + lk);
        #pragma unroll
        for (int nt = 0; nt < 4; ++nt) {
            bf16x8 b = *reinterpret_cast<const bf16x8*>(Bw + (size_t)(n0 + nt * 16 + lr) * K + ks * 32 + lk);
            acc[nt] = __builtin_amdgcn_mfma_f32_16x16x32_bf16(a, b, acc[nt], 0, 0, 0);
        }
    }
    #pragma unroll
    for (int nt = 0; nt < 4; ++nt) {
        #pragma unroll
        for (int r = 0; r < 4; ++r) {
            int row = m0 + wv * 16 + (l >> 4) * 4 + r;
            int col = n0 + nt * 16 + lr;
            float v = acc[nt][r];
            if (b0) v += b0[col];
            if (b1) v += b1[col];
            C[(size_t)row * N + col] = v;
        }
    }
}

// ---------------- recurrence: h_{t+1} = tanh(xp[:,t,:] + h_t @ W^T) ----------------
// grid: NG*JW blocks of 512 threads (8 waves). Block (g,jw): batches [g*16,g*16+16),
// output cols [jw*128, jw*128+128). W slice held in VGPRs as MFMA B-fragments.
// Cross-WG h exchange via parity-double-buffered global h_buf + release/acquire flags.
#define FLAG_STRIDE 32
__global__ __launch_bounds__(512, 2) void recur_kernel(
    const float* __restrict__ xp,        // [B][T][H] preactivation (incl. both biases)
    const unsigned short* __restrict__ w, // [H][H] bf16, row j (out), col k (in)
    unsigned short* __restrict__ out_bf, // [B][T][H] bf16 h outputs
    float* __restrict__ h_final,         // [B][H] f32 (hidden state output)
    unsigned short* __restrict__ h_buf,  // [2][B][H] bf16, pre-zeroed
    int* flags)                          // [NG*JW*FLAG_STRIDE] pre-zeroed
{
    const int bid = blockIdx.x;
    const int g  = bid / JW;
    const int jw = bid % JW;
    const int b0 = g * BS;
    const int j0 = jw * (H_ / JW);
    const int tid = threadIdx.x;
    const int wv = tid >> 6;     // 0..7, one 16-col N tile per wave
    const int l  = tid & 63;
    const int lr = l & 15;
    const int lk = (l >> 4) * 8;

    const int jcol = j0 + wv * 16 + lr;   // B-fragment col == epilogue col
    // resident B fragments: bw[ks] covers k = ks*32 + lk + [0,8)
    bf16x8 bw[16];
    #pragma unroll
    for (int ks = 0; ks < 16; ++ks)
        bw[ks] = *reinterpret_cast<const bf16x8*>(w + (size_t)jcol * H_ + ks * 32 + lk);

    const int arow = b0 + lr;             // A-fragment row (batch)
    const int erow_base = b0 + (l >> 4) * 4;

    for (int t = 0; t < T_; ++t) {
        if (t > 0) {
            if (tid < JW - 1) {
                int p = (jw + 1 + tid) % JW;
                while (__hip_atomic_load(&flags[(g * JW + p) * FLAG_STRIDE],
                                         __ATOMIC_ACQUIRE, __HIP_MEMORY_SCOPE_AGENT) < t) {
                    __builtin_amdgcn_s_sleep(2);
                }
            }
            __syncthreads();
            __threadfence();
        }
        const unsigned short* hb = h_buf + (size_t)(t & 1) * B_ * H_;
        bf16x8 af[16];
        #pragma unroll
        for (int ks = 0; ks < 16; ++ks)
            af[ks] = *reinterpret_cast<const bf16x8*>(hb + (size_t)arow * H_ + ks * 32 + lk);

        f32x4 acc0 = {0,0,0,0}, acc1 = {0,0,0,0};
        #pragma unroll
        for (int ks = 0; ks < 16; ks += 2) {
            acc0 = __builtin_amdgcn_mfma_f32_16x16x32_bf16(af[ks],     bw[ks],     acc0, 0, 0, 0);
            acc1 = __builtin_amdgcn_mfma_f32_16x16x32_bf16(af[ks + 1], bw[ks + 1], acc1, 0, 0, 0);
        }
        f32x4 acc = acc0 + acc1;

        unsigned short* hbn = h_buf + (size_t)((t + 1) & 1) * B_ * H_;
        #pragma unroll
        for (int r = 0; r < 4; ++r) {
            int row = erow_base + r;
            float pre = acc[r] + xp[((size_t)row * T_ + t) * H_ + jcol];
            float hv = tanhf(pre);
            unsigned short hb16 = f2bf(hv);
            hbn[(size_t)row * H_ + jcol] = hb16;
            out_bf[((size_t)row * T_ + t) * H_ + jcol] = hb16;
            if (t == T_ - 1) h_final[(size_t)row * H_ + jcol] = hv;
        }
        __threadfence();
        __syncthreads();
        if (tid == 0)
            __hip_atomic_store(&flags[bid * FLAG_STRIDE], t + 1,
                               __ATOMIC_RELEASE, __HIP_MEMORY_SCOPE_AGENT);
    }
}

// ---------------- workspace layout (bytes) ----------------
#define OFF_XBF    ((size_t)0)                     // 64*512*256 bf16 = 16777216
#define OFF_WIH0   ((size_t)16777216)              // 512*256 bf16   = 262144
#define OFF_WHH0   ((size_t)17039360)              // 512*512 bf16   = 524288
#define OFF_WIH1   ((size_t)17563648)              // 512*512 bf16   = 524288
#define OFF_WHH1   ((size_t)18087936)              // 512*512 bf16   = 524288
#define OFF_FCW    ((size_t)18612224)              // 256*512 bf16   = 262144
#define OFF_XP     ((size_t)18874368)              // 64*512*512 f32 = 67108864 (xp0 then xp1)
#define OFF_OUTBF  ((size_t)85983232)              // 64*512*512 bf16 = 33554432 (out0 then out1)
#define OFF_HBUF0  ((size_t)119537664)             // 2*64*512 bf16  = 131072
#define OFF_HBUF1  ((size_t)119668736)             // 131072
#define OFF_FLAGS  ((size_t)119799808)             // 2 * 16 * 32 ints = 4096
#define WS_NEED    ((size_t)119803904)

extern "C" void kernel_launch(void* const* d_in, const int* in_sizes, int n_in,
                              void* d_out, int out_size, void* d_ws, size_t ws_size,
                              hipStream_t stream) {
    if (ws_size < WS_NEED) return;
    const float* x     = (const float*)d_in[0];
    const float* w_ih0 = (const float*)d_in[1];
    const float* w_hh0 = (const float*)d_in[2];
    const float* b_ih0 = (const float*)d_in[3];
    const float* b_hh0 = (const float*)d_in[4];
    const float* w_ih1 = (const float*)d_in[5];
    const float* w_hh1 = (const float*)d_in[6];
    const float* b_ih1 = (const float*)d_in[7];
    const float* b_hh1 = (const float*)d_in[8];
    const float* fc_w  = (const float*)d_in[9];
    const float* fc_b  = (const float*)d_in[10];

    char* ws = (char*)d_ws;
    unsigned short* x_bf     = (unsigned short*)(ws + OFF_XBF);
    unsigned short* w_ih0_bf = (unsigned short*)(ws + OFF_WIH0);
    unsigned short* w_hh0_bf = (unsigned short*)(ws + OFF_WHH0);
    unsigned short* w_ih1_bf = (unsigned short*)(ws + OFF_WIH1);
    unsigned short* w_hh1_bf = (unsigned short*)(ws + OFF_WHH1);
    unsigned short* fc_w_bf  = (unsigned short*)(ws + OFF_FCW);
    float*          xp       = (float*)(ws + OFF_XP);
    unsigned short* out_bf   = (unsigned short*)(ws + OFF_OUTBF);
    unsigned short* h_buf0   = (unsigned short*)(ws + OFF_HBUF0);
    unsigned short* h_buf1   = (unsigned short*)(ws + OFF_HBUF1);
    int*            flags0   = (int*)(ws + OFF_FLAGS);
    int*            flags1   = flags0 + NG * JW * FLAG_STRIDE;

    float* out  = (float*)d_out;                 // [32768][256]
    float* hid0 = out + (size_t)B_ * T_ * O_;    // [64][512]
    float* hid1 = hid0 + (size_t)B_ * H_;

    // zero h double-buffers + flags (re-done every call -> replay-safe)
    hipMemsetAsync(ws + OFF_HBUF0, 0, 131072 * 2 + 4096, stream);

    // f32 -> bf16 converts
    auto cvt = [&](const float* in, unsigned short* o, int n) {
        int n4 = n / 4;
        cvt_kernel<<<(n4 + 255) / 256, 256, 0, stream>>>(in, o, n4);
    };
    cvt(x,     x_bf,     B_ * T_ * I_);
    cvt(w_ih0, w_ih0_bf, H_ * I_);
    cvt(w_hh0, w_hh0_bf, H_ * H_);
    cvt(w_ih1, w_ih1_bf, H_ * H_);
    cvt(w_hh1, w_hh1_bf, H_ * H_);
    cvt(fc_w,  fc_w_bf,  O_ * H_);

    const int M = B_ * T_;  // 32768

    // xp0 = x @ w_ih0^T + b_ih0 + b_hh0
    gemm_kernel<<<dim3(M / 64, H_ / 64), 256, 0, stream>>>(
        x_bf, w_ih0_bf, b_ih0, b_hh0, xp, M, H_, I_);

    // layer 0 recurrence
    recur_kernel<<<NG * JW, 512, 0, stream>>>(xp, w_hh0_bf, out_bf, hid0, h_buf0, flags0);

    // xp1 = out0 @ w_ih1^T + b_ih1 + b_hh1   (xp buffer reused)
    gemm_kernel<<<dim3(M / 64, H_ / 64), 256, 0, stream>>>(
        out_bf, w_ih1_bf, b_ih1, b_hh1, xp, M, H_, H_);

    // layer 1 recurrence (out_bf reused: its old contents were consumed by the gemm above)
    recur_kernel<<<NG * JW, 512, 0, stream>>>(xp, w_hh1_bf, out_bf, hid1, h_buf1, flags1);

    // out = out1 @ fc_w^T + fc_b
    gemm_kernel<<<dim3(M / 64, O_ / 64), 256, 0, stream>>>(
        out_bf, fc_w_bf, fc_b, nullptr, out, M, O_, H_);
}

// Round 3
// 11204.357 us; speedup vs baseline: 1.0500x; 1.0500x over previous
//
#include <hip/hip_runtime.h>

#define B_  64
#define T_  512
#define I_  256
#define H_  512
#define O_  256
#define JW  4      // j-split workgroups per group
#define BS  16     // batch rows per group (one 16-row M tile)
#define NG  (B_ / BS)  // 4 groups

typedef __attribute__((ext_vector_type(8))) __bf16 bf16x8;
typedef __attribute__((ext_vector_type(4))) float f32x4;

__device__ __forceinline__ unsigned short f2bf(float f) {
    unsigned int u = __float_as_uint(f);
    unsigned int r = (u + 0x7fffu + ((u >> 16) & 1u)) >> 16;
    return (unsigned short)r;
}

// ---------------- convert f32 -> bf16 (x4 vectorized) ----------------
__global__ void cvt_kernel(const float* __restrict__ in, unsigned short* __restrict__ out, int n4) {
    int i = blockIdx.x * blockDim.x + threadIdx.x;
    if (i >= n4) return;
    float4 f = reinterpret_cast<const float4*>(in)[i];
    ushort4 o;
    o.x = f2bf(f.x); o.y = f2bf(f.y); o.z = f2bf(f.z); o.w = f2bf(f.w);
    reinterpret_cast<ushort4*>(out)[i] = o;
}

// ---------------- generic GEMM: C[M][N] = A[M][K] @ Bw[N][K]^T + b0 + b1 ----------------
// block: 256 threads (4 waves), block tile 64M x 64N, wave tile 16M x 64N
__global__ __launch_bounds__(256) void gemm_kernel(
    const unsigned short* __restrict__ A,
    const unsigned short* __restrict__ Bw,
    const float* __restrict__ b0,
    const float* __restrict__ b1,
    float* __restrict__ C,
    int M, int N, int K)
{
    const int m0 = blockIdx.x * 64;
    const int n0 = blockIdx.y * 64;
    const int tid = threadIdx.x;
    const int wv = tid >> 6;
    const int l = tid & 63;
    const int lr = l & 15;
    const int lk = (l >> 4) * 8;
    const int arow = m0 + wv * 16 + lr;

    f32x4 acc[4] = {{0,0,0,0},{0,0,0,0},{0,0,0,0},{0,0,0,0}};
    const int nks = K / 32;
    for (int ks = 0; ks < nks; ++ks) {
        bf16x8 a = *reinterpret_cast<const bf16x8*>(A + (size_t)arow * K + ks * 32 + lk);
        #pragma unroll
        for (int nt = 0; nt < 4; ++nt) {
            bf16x8 b = *reinterpret_cast<const bf16x8*>(Bw + (size_t)(n0 + nt * 16 + lr) * K + ks * 32 + lk);
            acc[nt] = __builtin_amdgcn_mfma_f32_16x16x32_bf16(a, b, acc[nt], 0, 0, 0);
        }
    }
    #pragma unroll
    for (int nt = 0; nt < 4; ++nt) {
        #pragma unroll
        for (int r = 0; r < 4; ++r) {
            int row = m0 + wv * 16 + (l >> 4) * 4 + r;
            int col = n0 + nt * 16 + lr;
            float v = acc[nt][r];
            if (b0) v += b0[col];
            if (b1) v += b1[col];
            C[(size_t)row * N + col] = v;
        }
    }
}

// ---------------- recurrence: h_{t+1} = tanh(xp[:,t,:] + h_t @ W^T) ----------------
// grid: NG*JW blocks of 512 threads (8 waves). Block (g,jw): batches [g*16,g*16+16),
// output cols [jw*128, jw*128+128). W slice pinned in VGPRs as MFMA B-fragments.
// Cross-WG h exchange via parity-double-buffered global h_buf using RELAXED+AGENT
// atomics (sc1 ops coherent at MALL; NO fences -> no per-step L2 wb/inv).
#define FLAG_STRIDE 32
__global__ __launch_bounds__(512, 2) void recur_kernel(
    const float* __restrict__ xp,        // [B][T][H] preactivation (incl. both biases)
    const unsigned short* __restrict__ w, // [H][H] bf16, row j (out), col k (in)
    unsigned short* __restrict__ out_bf, // [B][T][H] bf16 h outputs
    float* __restrict__ h_final,         // [B][H] f32 (hidden state output)
    unsigned short* __restrict__ h_buf,  // [2][B][H] bf16, pre-zeroed
    int* flags)                          // [NG*JW*FLAG_STRIDE] pre-zeroed
{
    const int bid = blockIdx.x;
    const int g  = bid / JW;
    const int jw = bid % JW;
    const int b0 = g * BS;
    const int j0 = jw * (H_ / JW);
    const int tid = threadIdx.x;
    const int wv = tid >> 6;     // 0..7, one 16-col N tile per wave
    const int l  = tid & 63;
    const int lr = l & 15;
    const int lk = (l >> 4) * 8;

    const int jcol = j0 + wv * 16 + lr;   // B-fragment col == epilogue col
    // resident B fragments: bw[ks] covers k = ks*32 + lk + [0,8)
    bf16x8 bw[16];
    #pragma unroll
    for (int ks = 0; ks < 16; ++ks)
        bw[ks] = *reinterpret_cast<const bf16x8*>(w + (size_t)jcol * H_ + ks * 32 + lk);
    // pin the weight fragments in VGPRs: compiler may not rematerialize the loads
    #pragma unroll
    for (int ks = 0; ks < 16; ++ks)
        asm volatile("" : "+v"(bw[ks]));

    const int arow = b0 + lr;             // A-fragment row (batch)
    const int erow_base = b0 + (l >> 4) * 4;

    for (int t = 0; t < T_; ++t) {
        if (t > 0) {
            if (tid < JW - 1) {
                int p = (jw + 1 + tid) % JW;
                while (__hip_atomic_load(&flags[(g * JW + p) * FLAG_STRIDE],
                                         __ATOMIC_RELAXED, __HIP_MEMORY_SCOPE_AGENT) < t) {
                    __builtin_amdgcn_s_sleep(1);
                }
            }
            __syncthreads();
            asm volatile("" ::: "memory");  // compiler fence: keep af loads below the poll
        }
        const unsigned short* hb = h_buf + (size_t)(t & 1) * B_ * H_;
        // A fragments: sc1 loads straight from the coherence point (no stale L2)
        bf16x8 af[16];
        #pragma unroll
        for (int ks = 0; ks < 16; ++ks) {
            const unsigned long long* p =
                (const unsigned long long*)(hb + (size_t)arow * H_ + ks * 32 + lk);
            union { unsigned long long q[2]; bf16x8 v; } u;
            u.q[0] = __hip_atomic_load(p,     __ATOMIC_RELAXED, __HIP_MEMORY_SCOPE_AGENT);
            u.q[1] = __hip_atomic_load(p + 1, __ATOMIC_RELAXED, __HIP_MEMORY_SCOPE_AGENT);
            af[ks] = u.v;
        }

        f32x4 acc0 = {0,0,0,0}, acc1 = {0,0,0,0};
        #pragma unroll
        for (int ks = 0; ks < 16; ks += 2) {
            acc0 = __builtin_amdgcn_mfma_f32_16x16x32_bf16(af[ks],     bw[ks],     acc0, 0, 0, 0);
            acc1 = __builtin_amdgcn_mfma_f32_16x16x32_bf16(af[ks + 1], bw[ks + 1], acc1, 0, 0, 0);
        }
        f32x4 acc = acc0 + acc1;

        unsigned short* hbn = h_buf + (size_t)((t + 1) & 1) * B_ * H_;
        #pragma unroll
        for (int r = 0; r < 4; ++r) {
            int row = erow_base + r;
            float pre = acc[r] + xp[((size_t)row * T_ + t) * H_ + jcol];
            float hv = tanhf(pre);
            unsigned short hb16 = f2bf(hv);
            // pack (col, col+1) across adjacent lanes -> one u32 sc1 store from even lanes
            unsigned int mine = hb16;
            unsigned int other = __shfl_xor(mine, 1, 64);
            if (!(lr & 1)) {
                unsigned int packed = mine | (other << 16);
                __hip_atomic_store((unsigned int*)(hbn + (size_t)row * H_ + jcol), packed,
                                   __ATOMIC_RELAXED, __HIP_MEMORY_SCOPE_AGENT);
            }
            out_bf[((size_t)row * T_ + t) * H_ + jcol] = hb16;
            if (t == T_ - 1) h_final[(size_t)row * H_ + jcol] = hv;
        }
        // drain this wave's stores to the coherence point, then block barrier
        // (each wave executes the drain -> all h stores visible before flag set)
        asm volatile("s_waitcnt vmcnt(0)" ::: "memory");
        __syncthreads();
        if (tid == 0)
            __hip_atomic_store(&flags[bid * FLAG_STRIDE], t + 1,
                               __ATOMIC_RELAXED, __HIP_MEMORY_SCOPE_AGENT);
    }
}

// ---------------- workspace layout (bytes) ----------------
#define OFF_XBF    ((size_t)0)                     // 64*512*256 bf16 = 16777216
#define OFF_WIH0   ((size_t)16777216)              // 512*256 bf16   = 262144
#define OFF_WHH0   ((size_t)17039360)              // 512*512 bf16   = 524288
#define OFF_WIH1   ((size_t)17563648)              // 512*512 bf16   = 524288
#define OFF_WHH1   ((size_t)18087936)              // 512*512 bf16   = 524288
#define OFF_FCW    ((size_t)18612224)              // 256*512 bf16   = 262144
#define OFF_XP     ((size_t)18874368)              // 64*512*512 f32 = 67108864 (xp0 then xp1)
#define OFF_OUTBF  ((size_t)85983232)              // 64*512*512 bf16 = 33554432 (out0 then out1)
#define OFF_HBUF0  ((size_t)119537664)             // 2*64*512 bf16  = 131072
#define OFF_HBUF1  ((size_t)119668736)             // 131072
#define OFF_FLAGS  ((size_t)119799808)             // 2 * 16 * 32 ints = 4096
#define WS_NEED    ((size_t)119803904)

extern "C" void kernel_launch(void* const* d_in, const int* in_sizes, int n_in,
                              void* d_out, int out_size, void* d_ws, size_t ws_size,
                              hipStream_t stream) {
    if (ws_size < WS_NEED) return;
    const float* x     = (const float*)d_in[0];
    const float* w_ih0 = (const float*)d_in[1];
    const float* w_hh0 = (const float*)d_in[2];
    const float* b_ih0 = (const float*)d_in[3];
    const float* b_hh0 = (const float*)d_in[4];
    const float* w_ih1 = (const float*)d_in[5];
    const float* w_hh1 = (const float*)d_in[6];
    const float* b_ih1 = (const float*)d_in[7];
    const float* b_hh1 = (const float*)d_in[8];
    const float* fc_w  = (const float*)d_in[9];
    const float* fc_b  = (const float*)d_in[10];

    char* ws = (char*)d_ws;
    unsigned short* x_bf     = (unsigned short*)(ws + OFF_XBF);
    unsigned short* w_ih0_bf = (unsigned short*)(ws + OFF_WIH0);
    unsigned short* w_hh0_bf = (unsigned short*)(ws + OFF_WHH0);
    unsigned short* w_ih1_bf = (unsigned short*)(ws + OFF_WIH1);
    unsigned short* w_hh1_bf = (unsigned short*)(ws + OFF_WHH1);
    unsigned short* fc_w_bf  = (unsigned short*)(ws + OFF_FCW);
    float*          xp       = (float*)(ws + OFF_XP);
    unsigned short* out_bf   = (unsigned short*)(ws + OFF_OUTBF);
    unsigned short* h_buf0   = (unsigned short*)(ws + OFF_HBUF0);
    unsigned short* h_buf1   = (unsigned short*)(ws + OFF_HBUF1);
    int*            flags0   = (int*)(ws + OFF_FLAGS);
    int*            flags1   = flags0 + NG * JW * FLAG_STRIDE;

    float* out  = (float*)d_out;                 // [32768][256]
    float* hid0 = out + (size_t)B_ * T_ * O_;    // [64][512]
    float* hid1 = hid0 + (size_t)B_ * H_;

    // zero h double-buffers + flags (re-done every call -> replay-safe)
    hipMemsetAsync(ws + OFF_HBUF0, 0, 131072 * 2 + 4096, stream);

    // f32 -> bf16 converts
    auto cvt = [&](const float* in, unsigned short* o, int n) {
        int n4 = n / 4;
        cvt_kernel<<<(n4 + 255) / 256, 256, 0, stream>>>(in, o, n4);
    };
    cvt(x,     x_bf,     B_ * T_ * I_);
    cvt(w_ih0, w_ih0_bf, H_ * I_);
    cvt(w_hh0, w_hh0_bf, H_ * H_);
    cvt(w_ih1, w_ih1_bf, H_ * H_);
    cvt(w_hh1, w_hh1_bf, H_ * H_);
    cvt(fc_w,  fc_w_bf,  O_ * H_);

    const int M = B_ * T_;  // 32768

    // xp0 = x @ w_ih0^T + b_ih0 + b_hh0
    gemm_kernel<<<dim3(M / 64, H_ / 64), 256, 0, stream>>>(
        x_bf, w_ih0_bf, b_ih0, b_hh0, xp, M, H_, I_);

    // layer 0 recurrence
    recur_kernel<<<NG * JW, 512, 0, stream>>>(xp, w_hh0_bf, out_bf, hid0, h_buf0, flags0);

    // xp1 = out0 @ w_ih1^T + b_ih1 + b_hh1   (xp buffer reused)
    gemm_kernel<<<dim3(M / 64, H_ / 64), 256, 0, stream>>>(
        out_bf, w_ih1_bf, b_ih1, b_hh1, xp, M, H_, H_);

    // layer 1 recurrence (out_bf reused: its old contents were consumed by the gemm above)
    recur_kernel<<<NG * JW, 512, 0, stream>>>(xp, w_hh1_bf, out_bf, hid1, h_buf1, flags1);

    // out = out1 @ fc_w^T + fc_b
    gemm_kernel<<<dim3(M / 64, O_ / 64), 256, 0, stream>>>(
        out_bf, fc_w_bf, fc_b, nullptr, out, M, O_, H_);
}

// Round 5
// 5047.022 us; speedup vs baseline: 2.3310x; 2.2200x over previous
//
#include <hip/hip_runtime.h>

#define B_  64
#define T_  512
#define I_  256
#define H_  512
#define O_  256
#define JW  2      // j-split workgroups per group
#define BS  16     // batch rows per group (one 16-row M tile)
#define NG  (B_ / BS)  // 4 groups
#define FLAG_STRIDE 32

typedef __attribute__((ext_vector_type(8))) __bf16 bf16x8;
typedef __attribute__((ext_vector_type(4))) float f32x4;

__device__ __forceinline__ unsigned short f2bf(float f) {
    unsigned int u = __float_as_uint(f);
    unsigned int r = (u + 0x7fffu + ((u >> 16) & 1u)) >> 16;
    return (unsigned short)r;
}

__device__ __forceinline__ float tanh_fast(float x) {
    // tanh(x) = 1 - 2/(exp(2x)+1); err << bf16 ulp
    float e = __expf(2.0f * x);
    float d = e + 1.0f;
    float r;
    asm("v_rcp_f32 %0, %1" : "=v"(r) : "v"(d));
    return 1.0f - 2.0f * r;
}

// ---------------- convert f32 -> bf16 (x4 vectorized) ----------------
__global__ void cvt_kernel(const float* __restrict__ in, unsigned short* __restrict__ out, int n4) {
    int i = blockIdx.x * blockDim.x + threadIdx.x;
    if (i >= n4) return;
    float4 f = reinterpret_cast<const float4*>(in)[i];
    ushort4 o;
    o.x = f2bf(f.x); o.y = f2bf(f.y); o.z = f2bf(f.z); o.w = f2bf(f.w);
    reinterpret_cast<ushort4*>(out)[i] = o;
}

// ---------------- generic GEMM: C[M][N] = A[M][K] @ Bw[N][K]^T + b0 + b1 ----------------
__global__ __launch_bounds__(256) void gemm_kernel(
    const unsigned short* __restrict__ A,
    const unsigned short* __restrict__ Bw,
    const float* __restrict__ b0,
    const float* __restrict__ b1,
    float* __restrict__ C,
    int M, int N, int K)
{
    const int m0 = blockIdx.x * 64;
    const int n0 = blockIdx.y * 64;
    const int tid = threadIdx.x;
    const int wv = tid >> 6;
    const int l = tid & 63;
    const int lr = l & 15;
    const int lk = (l >> 4) * 8;
    const int arow = m0 + wv * 16 + lr;

    f32x4 acc[4] = {{0,0,0,0},{0,0,0,0},{0,0,0,0},{0,0,0,0}};
    const int nks = K / 32;
    for (int ks = 0; ks < nks; ++ks) {
        bf16x8 a = *reinterpret_cast<const bf16x8*>(A + (size_t)arow * K + ks * 32 + lk);
        #pragma unroll
        for (int nt = 0; nt < 4; ++nt) {
            bf16x8 b = *reinterpret_cast<const bf16x8*>(Bw + (size_t)(n0 + nt * 16 + lr) * K + ks * 32 + lk);
            acc[nt] = __builtin_amdgcn_mfma_f32_16x16x32_bf16(a, b, acc[nt], 0, 0, 0);
        }
    }
    #pragma unroll
    for (int nt = 0; nt < 4; ++nt) {
        #pragma unroll
        for (int r = 0; r < 4; ++r) {
            int row = m0 + wv * 16 + (l >> 4) * 4 + r;
            int col = n0 + nt * 16 + lr;
            float v = acc[nt][r];
            if (b0) v += b0[col];
            if (b1) v += b1[col];
            C[(size_t)row * N + col] = v;
        }
    }
}

// ---------------- recurrence ----------------
// Weight loads: 16 loads + waitcnt in ONE asm statement => outputs are complete
// values from the compiler's view (spills after are correct).
#define LDW16(NT) \
    asm volatile( \
        "global_load_dwordx4 %0, %16, %17 offset:0\n\t" \
        "global_load_dwordx4 %1, %16, %17 offset:64\n\t" \
        "global_load_dwordx4 %2, %16, %17 offset:128\n\t" \
        "global_load_dwordx4 %3, %16, %17 offset:192\n\t" \
        "global_load_dwordx4 %4, %16, %17 offset:256\n\t" \
        "global_load_dwordx4 %5, %16, %17 offset:320\n\t" \
        "global_load_dwordx4 %6, %16, %17 offset:384\n\t" \
        "global_load_dwordx4 %7, %16, %17 offset:448\n\t" \
        "global_load_dwordx4 %8, %16, %17 offset:512\n\t" \
        "global_load_dwordx4 %9, %16, %17 offset:576\n\t" \
        "global_load_dwordx4 %10, %16, %17 offset:640\n\t" \
        "global_load_dwordx4 %11, %16, %17 offset:704\n\t" \
        "global_load_dwordx4 %12, %16, %17 offset:768\n\t" \
        "global_load_dwordx4 %13, %16, %17 offset:832\n\t" \
        "global_load_dwordx4 %14, %16, %17 offset:896\n\t" \
        "global_load_dwordx4 %15, %16, %17 offset:960\n\t" \
        "s_waitcnt vmcnt(0)" \
        : "=&v"(bw[NT][0]), "=&v"(bw[NT][1]), "=&v"(bw[NT][2]), "=&v"(bw[NT][3]), \
          "=&v"(bw[NT][4]), "=&v"(bw[NT][5]), "=&v"(bw[NT][6]), "=&v"(bw[NT][7]), \
          "=&v"(bw[NT][8]), "=&v"(bw[NT][9]), "=&v"(bw[NT][10]), "=&v"(bw[NT][11]), \
          "=&v"(bw[NT][12]), "=&v"(bw[NT][13]), "=&v"(bw[NT][14]), "=&v"(bw[NT][15]) \
        : "v"(vbw[NT]), "s"(w))

#define ST_HW(I, IMM) \
    asm volatile("global_store_dword %0, %1, %2 offset:" IMM " sc0 sc1" :: "v"(vh_p), "v"(pk[I]), "s"(h_buf) : "memory")
#define ST_OW(I, R, IMM) \
    asm volatile("global_store_dword %0, %1, %2 offset:" IMM :: "v"(vout[R]), "v"(pk[I]), "s"(out_bf) : "memory")

__global__ __launch_bounds__(256, 1) void recur_kernel(
    const float* __restrict__ xp,         // [B][T][H] f32 preactivation (incl. biases)
    const unsigned short* __restrict__ w, // [H][H] bf16
    unsigned short* __restrict__ out_bf,  // [B][T][H] bf16
    float* __restrict__ h_final,          // [B][H] f32
    unsigned short* __restrict__ h_buf,   // [2][B][H] bf16, pre-zeroed
    int* __restrict__ flags)              // pre-zeroed
{
    const int bid = blockIdx.x;
    const int g   = bid >> 1;
    const int jw  = bid & 1;
    const int b0  = g * BS;
    const int tid = threadIdx.x;
    const int wv  = tid >> 6;
    const int l   = tid & 63;
    const int lr  = l & 15;
    const int lk  = (l >> 4) * 8;
    const int jn0 = jw * 256 + wv * 64;      // wave's column base
    const int arow = b0 + lr;                // A-fragment row
    const int erow = b0 + (l >> 4) * 4;      // epilogue row base

    // ---- weights -> VGPRs, once (4 self-contained statements) ----
    bf16x8 bw[4][16];
    unsigned int vbw[4];
    #pragma unroll
    for (int nt = 0; nt < 4; ++nt)
        vbw[nt] = (unsigned)((jn0 + nt * 16 + lr) * (H_ * 2) + lk * 2);
    LDW16(0); LDW16(1); LDW16(2); LDW16(3);

    // ---- per-thread 32-bit voffsets ----
    unsigned int vxpr[4], vout[4];
    #pragma unroll
    for (int r = 0; r < 4; ++r) {
        vxpr[r] = (unsigned)((((erow + r) * T_) * H_ + jn0 + lr) * 4);
        vout[r] = (unsigned)(((erow + r) * T_) * H_ * 2 + (jn0 + lr) * 2);
    }
    const unsigned int vaf0 = (unsigned)(arow * (H_ * 2) + lk * 2);
    const unsigned int vhs0 = (unsigned)(erow * (H_ * 2) + (jn0 + lr) * 2);
    const unsigned int fpeer = (unsigned)((bid ^ 1) * FLAG_STRIDE * 4);
    const unsigned int fself = (unsigned)(bid * FLAG_STRIDE * 4);

    for (int t = 0; t < T_; ++t) {
        if (t > 0) {
            if (tid == 0) {
                int fv;
                do {
                    asm volatile("global_load_dword %0, %1, %2 sc0 sc1\n\ts_waitcnt vmcnt(0)"
                                 : "=v"(fv) : "v"(fpeer), "s"(flags) : "memory");
                } while (fv < t);
            }
            __syncthreads();
        }
        unsigned int vaf_p = vaf0 + ((unsigned)(t & 1) << 16);
        // ONE asm statement: 16 xp loads (HBM) + 16 h loads (MALL, sc0 sc1),
        // all in flight together, one waitcnt => outputs complete on exit.
        float xpr[16];
        bf16x8 af[16];
        asm volatile(
            "global_load_dword %0, %32, %36\n\t"
            "global_load_dword %1, %33, %36\n\t"
            "global_load_dword %2, %34, %36\n\t"
            "global_load_dword %3, %35, %36\n\t"
            "global_load_dword %4, %32, %36 offset:64\n\t"
            "global_load_dword %5, %33, %36 offset:64\n\t"
            "global_load_dword %6, %34, %36 offset:64\n\t"
            "global_load_dword %7, %35, %36 offset:64\n\t"
            "global_load_dword %8, %32, %36 offset:128\n\t"
            "global_load_dword %9, %33, %36 offset:128\n\t"
            "global_load_dword %10, %34, %36 offset:128\n\t"
            "global_load_dword %11, %35, %36 offset:128\n\t"
            "global_load_dword %12, %32, %36 offset:192\n\t"
            "global_load_dword %13, %33, %36 offset:192\n\t"
            "global_load_dword %14, %34, %36 offset:192\n\t"
            "global_load_dword %15, %35, %36 offset:192\n\t"
            "global_load_dwordx4 %16, %37, %38 sc0 sc1\n\t"
            "global_load_dwordx4 %17, %37, %38 offset:64 sc0 sc1\n\t"
            "global_load_dwordx4 %18, %37, %38 offset:128 sc0 sc1\n\t"
            "global_load_dwordx4 %19, %37, %38 offset:192 sc0 sc1\n\t"
            "global_load_dwordx4 %20, %37, %38 offset:256 sc0 sc1\n\t"
            "global_load_dwordx4 %21, %37, %38 offset:320 sc0 sc1\n\t"
            "global_load_dwordx4 %22, %37, %38 offset:384 sc0 sc1\n\t"
            "global_load_dwordx4 %23, %37, %38 offset:448 sc0 sc1\n\t"
            "global_load_dwordx4 %24, %37, %38 offset:512 sc0 sc1\n\t"
            "global_load_dwordx4 %25, %37, %38 offset:576 sc0 sc1\n\t"
            "global_load_dwordx4 %26, %37, %38 offset:640 sc0 sc1\n\t"
            "global_load_dwordx4 %27, %37, %38 offset:704 sc0 sc1\n\t"
            "global_load_dwordx4 %28, %37, %38 offset:768 sc0 sc1\n\t"
            "global_load_dwordx4 %29, %37, %38 offset:832 sc0 sc1\n\t"
            "global_load_dwordx4 %30, %37, %38 offset:896 sc0 sc1\n\t"
            "global_load_dwordx4 %31, %37, %38 offset:960 sc0 sc1\n\t"
            "s_waitcnt vmcnt(0)"
            : "=&v"(xpr[0]), "=&v"(xpr[1]), "=&v"(xpr[2]), "=&v"(xpr[3]),
              "=&v"(xpr[4]), "=&v"(xpr[5]), "=&v"(xpr[6]), "=&v"(xpr[7]),
              "=&v"(xpr[8]), "=&v"(xpr[9]), "=&v"(xpr[10]), "=&v"(xpr[11]),
              "=&v"(xpr[12]), "=&v"(xpr[13]), "=&v"(xpr[14]), "=&v"(xpr[15]),
              "=&v"(af[0]), "=&v"(af[1]), "=&v"(af[2]), "=&v"(af[3]),
              "=&v"(af[4]), "=&v"(af[5]), "=&v"(af[6]), "=&v"(af[7]),
              "=&v"(af[8]), "=&v"(af[9]), "=&v"(af[10]), "=&v"(af[11]),
              "=&v"(af[12]), "=&v"(af[13]), "=&v"(af[14]), "=&v"(af[15])
            : "v"(vxpr[0]), "v"(vxpr[1]), "v"(vxpr[2]), "v"(vxpr[3]),
              "s"(xp), "v"(vaf_p), "s"(h_buf));
        __builtin_amdgcn_sched_barrier(0);

        f32x4 acc[4] = {{0,0,0,0},{0,0,0,0},{0,0,0,0},{0,0,0,0}};
        #pragma unroll
        for (int ks = 0; ks < 16; ++ks) {
            acc[0] = __builtin_amdgcn_mfma_f32_16x16x32_bf16(af[ks], bw[0][ks], acc[0], 0, 0, 0);
            acc[1] = __builtin_amdgcn_mfma_f32_16x16x32_bf16(af[ks], bw[1][ks], acc[1], 0, 0, 0);
            acc[2] = __builtin_amdgcn_mfma_f32_16x16x32_bf16(af[ks], bw[2][ks], acc[2], 0, 0, 0);
            acc[3] = __builtin_amdgcn_mfma_f32_16x16x32_bf16(af[ks], bw[3][ks], acc[3], 0, 0, 0);
        }

        unsigned int vh_p = vhs0 + ((unsigned)((t + 1) & 1) << 16);
        unsigned int pk[16];
        #pragma unroll
        for (int nt = 0; nt < 4; ++nt)
            #pragma unroll
            for (int r = 0; r < 4; ++r) {
                int i = nt * 4 + r;
                float pre = acc[nt][r] + xpr[i];
                float hv = tanh_fast(pre);
                if (t == T_ - 1)
                    h_final[(size_t)(erow + r) * H_ + jn0 + nt * 16 + lr] = hv;
                unsigned int mine = f2bf(hv);
                unsigned int oth = (unsigned int)__shfl_xor((int)mine, 1, 64);
                pk[i] = mine | (oth << 16);
            }
        if (!(lr & 1)) {
            ST_HW(0,"0");   ST_HW(1,"1024"); ST_HW(2,"2048");  ST_HW(3,"3072");
            ST_HW(4,"32");  ST_HW(5,"1056"); ST_HW(6,"2080");  ST_HW(7,"3104");
            ST_HW(8,"64");  ST_HW(9,"1088"); ST_HW(10,"2112"); ST_HW(11,"3136");
            ST_HW(12,"96"); ST_HW(13,"1120");ST_HW(14,"2144"); ST_HW(15,"3168");
            ST_OW(0,0,"0");  ST_OW(1,1,"0");  ST_OW(2,2,"0");  ST_OW(3,3,"0");
            ST_OW(4,0,"32"); ST_OW(5,1,"32"); ST_OW(6,2,"32"); ST_OW(7,3,"32");
            ST_OW(8,0,"64"); ST_OW(9,1,"64"); ST_OW(10,2,"64");ST_OW(11,3,"64");
            ST_OW(12,0,"96");ST_OW(13,1,"96");ST_OW(14,2,"96");ST_OW(15,3,"96");
        }
        // drain stores, barrier, release flag
        asm volatile("s_waitcnt vmcnt(0)" ::: "memory");
        __syncthreads();
        if (tid == 0) {
            int nv = t + 1;
            asm volatile("global_store_dword %0, %1, %2 sc0 sc1"
                         :: "v"(fself), "v"(nv), "s"(flags) : "memory");
        }
        #pragma unroll
        for (int r = 0; r < 4; ++r) { vxpr[r] += H_ * 4; vout[r] += H_ * 2; }
    }
}

// ---------------- workspace layout (bytes) ----------------
#define OFF_XBF    ((size_t)0)
#define OFF_WIH0   ((size_t)16777216)
#define OFF_WHH0   ((size_t)17039360)
#define OFF_WIH1   ((size_t)17563648)
#define OFF_WHH1   ((size_t)18087936)
#define OFF_FCW    ((size_t)18612224)
#define OFF_XP     ((size_t)18874368)
#define OFF_OUTBF  ((size_t)85983232)
#define OFF_HBUF0  ((size_t)119537664)
#define OFF_HBUF1  ((size_t)119668736)
#define OFF_FLAGS  ((size_t)119799808)
#define WS_NEED    ((size_t)119803904)

extern "C" void kernel_launch(void* const* d_in, const int* in_sizes, int n_in,
                              void* d_out, int out_size, void* d_ws, size_t ws_size,
                              hipStream_t stream) {
    if (ws_size < WS_NEED) return;
    const float* x     = (const float*)d_in[0];
    const float* w_ih0 = (const float*)d_in[1];
    const float* w_hh0 = (const float*)d_in[2];
    const float* b_ih0 = (const float*)d_in[3];
    const float* b_hh0 = (const float*)d_in[4];
    const float* w_ih1 = (const float*)d_in[5];
    const float* w_hh1 = (const float*)d_in[6];
    const float* b_ih1 = (const float*)d_in[7];
    const float* b_hh1 = (const float*)d_in[8];
    const float* fc_w  = (const float*)d_in[9];
    const float* fc_b  = (const float*)d_in[10];

    char* ws = (char*)d_ws;
    unsigned short* x_bf     = (unsigned short*)(ws + OFF_XBF);
    unsigned short* w_ih0_bf = (unsigned short*)(ws + OFF_WIH0);
    unsigned short* w_hh0_bf = (unsigned short*)(ws + OFF_WHH0);
    unsigned short* w_ih1_bf = (unsigned short*)(ws + OFF_WIH1);
    unsigned short* w_hh1_bf = (unsigned short*)(ws + OFF_WHH1);
    unsigned short* fc_w_bf  = (unsigned short*)(ws + OFF_FCW);
    float*          xp       = (float*)(ws + OFF_XP);
    unsigned short* out_bf   = (unsigned short*)(ws + OFF_OUTBF);
    unsigned short* h_buf0   = (unsigned short*)(ws + OFF_HBUF0);
    unsigned short* h_buf1   = (unsigned short*)(ws + OFF_HBUF1);
    int*            flags0   = (int*)(ws + OFF_FLAGS);
    int*            flags1   = flags0 + NG * JW * FLAG_STRIDE;

    float* out  = (float*)d_out;
    float* hid0 = out + (size_t)B_ * T_ * O_;
    float* hid1 = hid0 + (size_t)B_ * H_;

    hipMemsetAsync(ws + OFF_HBUF0, 0, 131072 * 2 + 4096, stream);

    auto cvt = [&](const float* in, unsigned short* o, int n) {
        int n4 = n / 4;
        cvt_kernel<<<(n4 + 255) / 256, 256, 0, stream>>>(in, o, n4);
    };
    cvt(x,     x_bf,     B_ * T_ * I_);
    cvt(w_ih0, w_ih0_bf, H_ * I_);
    cvt(w_hh0, w_hh0_bf, H_ * H_);
    cvt(w_ih1, w_ih1_bf, H_ * H_);
    cvt(w_hh1, w_hh1_bf, H_ * H_);
    cvt(fc_w,  fc_w_bf,  O_ * H_);

    const int M = B_ * T_;

    gemm_kernel<<<dim3(M / 64, H_ / 64), 256, 0, stream>>>(
        x_bf, w_ih0_bf, b_ih0, b_hh0, xp, M, H_, I_);

    recur_kernel<<<NG * JW, 256, 0, stream>>>(xp, w_hh0_bf, out_bf, hid0, h_buf0, flags0);

    gemm_kernel<<<dim3(M / 64, H_ / 64), 256, 0, stream>>>(
        out_bf, w_ih1_bf, b_ih1, b_hh1, xp, M, H_, H_);

    recur_kernel<<<NG * JW, 256, 0, stream>>>(xp, w_hh1_bf, out_bf, hid1, h_buf1, flags1);

    gemm_kernel<<<dim3(M / 64, O_ / 64), 256, 0, stream>>>(
        out_bf, fc_w_bf, fc_b, nullptr, out, M, O_, H_);
}

// Round 6
// 4439.402 us; speedup vs baseline: 2.6501x; 1.1369x over previous
//
#include <hip/hip_runtime.h>

#define B_  64
#define T_  512
#define I_  256
#define H_  512
#define O_  256
#define JW  2      // j-split workgroups per group
#define BS  16     // batch rows per group (one 16-row M tile)
#define NG  (B_ / BS)  // 4 groups
#define FLAG_STRIDE 32

typedef __attribute__((ext_vector_type(8))) __bf16 bf16x8;
typedef __attribute__((ext_vector_type(4))) float f32x4;

__device__ __forceinline__ unsigned short f2bf(float f) {
    unsigned int u = __float_as_uint(f);
    unsigned int r = (u + 0x7fffu + ((u >> 16) & 1u)) >> 16;
    return (unsigned short)r;
}

__device__ __forceinline__ float tanh_fast(float x) {
    // tanh(x) = 1 - 2/(exp(2x)+1); err << bf16 ulp
    float e = __expf(2.0f * x);
    float d = e + 1.0f;
    float r;
    asm("v_rcp_f32 %0, %1" : "=v"(r) : "v"(d));
    return 1.0f - 2.0f * r;
}

// ---------------- convert f32 -> bf16 (x4 vectorized) ----------------
__global__ void cvt_kernel(const float* __restrict__ in, unsigned short* __restrict__ out, int n4) {
    int i = blockIdx.x * blockDim.x + threadIdx.x;
    if (i >= n4) return;
    float4 f = reinterpret_cast<const float4*>(in)[i];
    ushort4 o;
    o.x = f2bf(f.x); o.y = f2bf(f.y); o.z = f2bf(f.z); o.w = f2bf(f.w);
    reinterpret_cast<ushort4*>(out)[i] = o;
}

// ---------------- generic GEMM: C[M][N] = A[M][K] @ Bw[N][K]^T + b0 + b1 ----------------
__global__ __launch_bounds__(256) void gemm_kernel(
    const unsigned short* __restrict__ A,
    const unsigned short* __restrict__ Bw,
    const float* __restrict__ b0,
    const float* __restrict__ b1,
    float* __restrict__ C,
    int M, int N, int K)
{
    const int m0 = blockIdx.x * 64;
    const int n0 = blockIdx.y * 64;
    const int tid = threadIdx.x;
    const int wv = tid >> 6;
    const int l = tid & 63;
    const int lr = l & 15;
    const int lk = (l >> 4) * 8;
    const int arow = m0 + wv * 16 + lr;

    f32x4 acc[4] = {{0,0,0,0},{0,0,0,0},{0,0,0,0},{0,0,0,0}};
    const int nks = K / 32;
    for (int ks = 0; ks < nks; ++ks) {
        bf16x8 a = *reinterpret_cast<const bf16x8*>(A + (size_t)arow * K + ks * 32 + lk);
        #pragma unroll
        for (int nt = 0; nt < 4; ++nt) {
            bf16x8 b = *reinterpret_cast<const bf16x8*>(Bw + (size_t)(n0 + nt * 16 + lr) * K + ks * 32 + lk);
            acc[nt] = __builtin_amdgcn_mfma_f32_16x16x32_bf16(a, b, acc[nt], 0, 0, 0);
        }
    }
    #pragma unroll
    for (int nt = 0; nt < 4; ++nt) {
        #pragma unroll
        for (int r = 0; r < 4; ++r) {
            int row = m0 + wv * 16 + (l >> 4) * 4 + r;
            int col = n0 + nt * 16 + lr;
            float v = acc[nt][r];
            if (b0) v += b0[col];
            if (b1) v += b1[col];
            C[(size_t)row * N + col] = v;
        }
    }
}

// ---------------- recurrence ----------------
// 8 blocks x 256 thr. Block (g,jw): batch rows [g*16,+16), cols [jw*256,+256).
// Own-half h staged in LDS (544B-padded rows); peer-half via MALL (sc0 sc1).
// Own-half MFMA overlaps the peer-flag poll. h-store drain is a counted
// vmcnt(16) that excludes out_bf HBM stores.
#define LDW8(ARR, BASE) \
    asm volatile( \
        "global_load_dwordx4 %0, %8, %9 offset:0\n\t" \
        "global_load_dwordx4 %1, %8, %9 offset:64\n\t" \
        "global_load_dwordx4 %2, %8, %9 offset:128\n\t" \
        "global_load_dwordx4 %3, %8, %9 offset:192\n\t" \
        "global_load_dwordx4 %4, %8, %9 offset:256\n\t" \
        "global_load_dwordx4 %5, %8, %9 offset:320\n\t" \
        "global_load_dwordx4 %6, %8, %9 offset:384\n\t" \
        "global_load_dwordx4 %7, %8, %9 offset:448\n\t" \
        "s_waitcnt vmcnt(0)" \
        : "=&v"(ARR[0]), "=&v"(ARR[1]), "=&v"(ARR[2]), "=&v"(ARR[3]), \
          "=&v"(ARR[4]), "=&v"(ARR[5]), "=&v"(ARR[6]), "=&v"(ARR[7]) \
        : "v"(BASE), "s"(w))

// epilogue store bundle: 16 h stores (MALL) FIRST, 16 out stores (HBM) second,
// counted wait vmcnt(16) -> only h stores drained before the flag release.
#define STORE_BUNDLE(PK, VHP, VOUT) \
    asm volatile( \
        "global_store_dword %16, %0, %21 sc0 sc1\n\t" \
        "global_store_dword %16, %1, %21 offset:1024 sc0 sc1\n\t" \
        "global_store_dword %16, %2, %21 offset:2048 sc0 sc1\n\t" \
        "global_store_dword %16, %3, %21 offset:3072 sc0 sc1\n\t" \
        "global_store_dword %16, %4, %21 offset:32 sc0 sc1\n\t" \
        "global_store_dword %16, %5, %21 offset:1056 sc0 sc1\n\t" \
        "global_store_dword %16, %6, %21 offset:2080 sc0 sc1\n\t" \
        "global_store_dword %16, %7, %21 offset:3104 sc0 sc1\n\t" \
        "global_store_dword %16, %8, %21 offset:64 sc0 sc1\n\t" \
        "global_store_dword %16, %9, %21 offset:1088 sc0 sc1\n\t" \
        "global_store_dword %16, %10, %21 offset:2112 sc0 sc1\n\t" \
        "global_store_dword %16, %11, %21 offset:3136 sc0 sc1\n\t" \
        "global_store_dword %16, %12, %21 offset:96 sc0 sc1\n\t" \
        "global_store_dword %16, %13, %21 offset:1120 sc0 sc1\n\t" \
        "global_store_dword %16, %14, %21 offset:2144 sc0 sc1\n\t" \
        "global_store_dword %16, %15, %21 offset:3168 sc0 sc1\n\t" \
        "global_store_dword %17, %0, %22\n\t" \
        "global_store_dword %18, %1, %22\n\t" \
        "global_store_dword %19, %2, %22\n\t" \
        "global_store_dword %20, %3, %22\n\t" \
        "global_store_dword %17, %4, %22 offset:32\n\t" \
        "global_store_dword %18, %5, %22 offset:32\n\t" \
        "global_store_dword %19, %6, %22 offset:32\n\t" \
        "global_store_dword %20, %7, %22 offset:32\n\t" \
        "global_store_dword %17, %8, %22 offset:64\n\t" \
        "global_store_dword %18, %9, %22 offset:64\n\t" \
        "global_store_dword %19, %10, %22 offset:64\n\t" \
        "global_store_dword %20, %11, %22 offset:64\n\t" \
        "global_store_dword %17, %12, %22 offset:96\n\t" \
        "global_store_dword %18, %13, %22 offset:96\n\t" \
        "global_store_dword %19, %14, %22 offset:96\n\t" \
        "global_store_dword %20, %15, %22 offset:96\n\t" \
        "s_waitcnt vmcnt(16)" \
        :: "v"(PK[0]), "v"(PK[1]), "v"(PK[2]), "v"(PK[3]), \
           "v"(PK[4]), "v"(PK[5]), "v"(PK[6]), "v"(PK[7]), \
           "v"(PK[8]), "v"(PK[9]), "v"(PK[10]), "v"(PK[11]), \
           "v"(PK[12]), "v"(PK[13]), "v"(PK[14]), "v"(PK[15]), \
           "v"(VHP), "v"(VOUT[0]), "v"(VOUT[1]), "v"(VOUT[2]), "v"(VOUT[3]), \
           "s"(h_buf), "s"(out_bf) \
        : "memory")

__global__ __launch_bounds__(256, 1) void recur_kernel(
    const float* __restrict__ xp,         // [B][T][H] f32 preactivation (incl. biases)
    const unsigned short* __restrict__ w, // [H][H] bf16
    unsigned short* __restrict__ out_bf,  // [B][T][H] bf16
    float* __restrict__ h_final,          // [B][H] f32
    unsigned short* __restrict__ h_buf,   // [2][B][H] bf16, pre-zeroed
    int* __restrict__ flags)              // pre-zeroed
{
    // own-half h staging: 16 rows x 256 cols bf16, row stride 272 ushorts (544 B)
    // 544 B = 136 words == 8 (mod 32 banks) -> rows spread banks, b128 reads ~conflict-free
    __shared__ __align__(16) unsigned short lds[16 * 272];

    const int bid = blockIdx.x;
    const int g   = bid >> 1;
    const int jw  = bid & 1;
    const int pjw = jw ^ 1;
    const int b0  = g * BS;
    const int tid = threadIdx.x;
    const int wv  = tid >> 6;
    const int l   = tid & 63;
    const int lr  = l & 15;
    const int lk  = (l >> 4) * 8;
    const int jn0 = jw * 256 + wv * 64;      // wave's global column base
    const int arow = b0 + lr;                // A-fragment row (batch)
    const int erow_l = (l >> 4) * 4;         // epilogue row base (group-local)
    const int erow_g = b0 + erow_l;

    // ---- weights -> VGPRs, once; own-ks half and peer-ks half separately ----
    bf16x8 bwo[4][8], bwp[4][8];
    #pragma unroll
    for (int nt = 0; nt < 4; ++nt) {
        unsigned int vo = (unsigned)((jn0 + nt * 16 + lr) * (H_ * 2) + jw  * 512 + lk * 2);
        unsigned int vp = (unsigned)((jn0 + nt * 16 + lr) * (H_ * 2) + pjw * 512 + lk * 2);
        LDW8(bwo[nt], vo);
        LDW8(bwp[nt], vp);
    }

    // ---- per-thread 32-bit voffsets ----
    unsigned int vxpr[4], vout[4];
    #pragma unroll
    for (int r = 0; r < 4; ++r) {
        vxpr[r] = (unsigned)((((erow_g + r) * T_) * H_ + jn0 + lr) * 4);
        vout[r] = (unsigned)(((erow_g + r) * T_) * H_ * 2 + (jn0 + lr) * 2);
    }
    const unsigned int vaf0p = (unsigned)(arow * (H_ * 2) + pjw * 512 + lk * 2);
    const unsigned int vhs0  = (unsigned)(erow_g * (H_ * 2) + (jn0 + lr) * 2);
    const unsigned int fpeer = (unsigned)((bid ^ 1) * FLAG_STRIDE * 4);
    const unsigned int fself = (unsigned)(bid * FLAG_STRIDE * 4);
    const int cb = wv * 32 + (lr >> 1);      // LDS u32 col base for epilogue writes

    // ================= t = 0 peel: h0 = 0 -> h1 = tanh(xp[0]) =================
    {
        float xpr[16];
        asm volatile(
            "global_load_dword %0, %16, %20\n\t"
            "global_load_dword %1, %17, %20\n\t"
            "global_load_dword %2, %18, %20\n\t"
            "global_load_dword %3, %19, %20\n\t"
            "global_load_dword %4, %16, %20 offset:64\n\t"
            "global_load_dword %5, %17, %20 offset:64\n\t"
            "global_load_dword %6, %18, %20 offset:64\n\t"
            "global_load_dword %7, %19, %20 offset:64\n\t"
            "global_load_dword %8, %16, %20 offset:128\n\t"
            "global_load_dword %9, %17, %20 offset:128\n\t"
            "global_load_dword %10, %18, %20 offset:128\n\t"
            "global_load_dword %11, %19, %20 offset:128\n\t"
            "global_load_dword %12, %16, %20 offset:192\n\t"
            "global_load_dword %13, %17, %20 offset:192\n\t"
            "global_load_dword %14, %18, %20 offset:192\n\t"
            "global_load_dword %15, %19, %20 offset:192\n\t"
            "s_waitcnt vmcnt(0)"
            : "=&v"(xpr[0]), "=&v"(xpr[1]), "=&v"(xpr[2]), "=&v"(xpr[3]),
              "=&v"(xpr[4]), "=&v"(xpr[5]), "=&v"(xpr[6]), "=&v"(xpr[7]),
              "=&v"(xpr[8]), "=&v"(xpr[9]), "=&v"(xpr[10]), "=&v"(xpr[11]),
              "=&v"(xpr[12]), "=&v"(xpr[13]), "=&v"(xpr[14]), "=&v"(xpr[15])
            : "v"(vxpr[0]), "v"(vxpr[1]), "v"(vxpr[2]), "v"(vxpr[3]), "s"(xp));

        unsigned int pk[16];
        #pragma unroll
        for (int nt = 0; nt < 4; ++nt)
            #pragma unroll
            for (int r = 0; r < 4; ++r) {
                int i = nt * 4 + r;
                float hv = tanh_fast(xpr[i]);
                unsigned int mine = f2bf(hv);
                unsigned int oth = (unsigned int)__shfl_xor((int)mine, 1, 64);
                pk[i] = mine | (oth << 16);
            }
        if (!(lr & 1)) {
            unsigned int* lw = (unsigned int*)lds;
            #pragma unroll
            for (int nt = 0; nt < 4; ++nt)
                #pragma unroll
                for (int r = 0; r < 4; ++r)
                    lw[(erow_l + r) * 136 + cb + nt * 8] = pk[nt * 4 + r];
            unsigned int vh_p = vhs0 + (1u << 16);
            STORE_BUNDLE(pk, vh_p, vout);
        }
        __syncthreads();
        if (tid == 0) {
            int nv = 1;
            asm volatile("global_store_dword %0, %1, %2 sc0 sc1"
                         :: "v"(fself), "v"(nv), "s"(flags) : "memory");
        }
        #pragma unroll
        for (int r = 0; r < 4; ++r) { vxpr[r] += H_ * 4; vout[r] += H_ * 2; }
    }

    // ================= main loop t = 1..T-1 =================
    for (int t = 1; t < T_; ++t) {
        // A: own-half A-fragments from LDS + own-half MFMA (independent of peer)
        f32x4 acc[4] = {{0,0,0,0},{0,0,0,0},{0,0,0,0},{0,0,0,0}};
        bf16x8 afo[8];
        const unsigned short* lrb = lds + lr * 272 + lk;
        #pragma unroll
        for (int i = 0; i < 8; ++i)
            afo[i] = *reinterpret_cast<const bf16x8*>(lrb + i * 32);
        #pragma unroll
        for (int i = 0; i < 8; ++i) {
            acc[0] = __builtin_amdgcn_mfma_f32_16x16x32_bf16(afo[i], bwo[0][i], acc[0], 0, 0, 0);
            acc[1] = __builtin_amdgcn_mfma_f32_16x16x32_bf16(afo[i], bwo[1][i], acc[1], 0, 0, 0);
            acc[2] = __builtin_amdgcn_mfma_f32_16x16x32_bf16(afo[i], bwo[2][i], acc[2], 0, 0, 0);
            acc[3] = __builtin_amdgcn_mfma_f32_16x16x32_bf16(afo[i], bwo[3][i], acc[3], 0, 0, 0);
        }
        __builtin_amdgcn_sched_barrier(0);

        // B: wait for the peer's step-t flag
        if (tid == 0) {
            int fv;
            do {
                asm volatile("global_load_dword %0, %1, %2 sc0 sc1\n\ts_waitcnt vmcnt(0)"
                             : "=v"(fv) : "v"(fpeer), "s"(flags) : "memory");
            } while (fv < t);
        }
        __syncthreads();

        // C: xp loads (HBM) + peer-half h loads (MALL), concurrent, one wait
        float xpr[16];
        bf16x8 afp[8];
        {
            const unsigned int vafp = vaf0p + ((unsigned)(t & 1) << 16);
            asm volatile(
                "global_load_dword %0, %24, %28\n\t"
                "global_load_dword %1, %25, %28\n\t"
                "global_load_dword %2, %26, %28\n\t"
                "global_load_dword %3, %27, %28\n\t"
                "global_load_dword %4, %24, %28 offset:64\n\t"
                "global_load_dword %5, %25, %28 offset:64\n\t"
                "global_load_dword %6, %26, %28 offset:64\n\t"
                "global_load_dword %7, %27, %28 offset:64\n\t"
                "global_load_dword %8, %24, %28 offset:128\n\t"
                "global_load_dword %9, %25, %28 offset:128\n\t"
                "global_load_dword %10, %26, %28 offset:128\n\t"
                "global_load_dword %11, %27, %28 offset:128\n\t"
                "global_load_dword %12, %24, %28 offset:192\n\t"
                "global_load_dword %13, %25, %28 offset:192\n\t"
                "global_load_dword %14, %26, %28 offset:192\n\t"
                "global_load_dword %15, %27, %28 offset:192\n\t"
                "global_load_dwordx4 %16, %29, %30 sc0 sc1\n\t"
                "global_load_dwordx4 %17, %29, %30 offset:64 sc0 sc1\n\t"
                "global_load_dwordx4 %18, %29, %30 offset:128 sc0 sc1\n\t"
                "global_load_dwordx4 %19, %29, %30 offset:192 sc0 sc1\n\t"
                "global_load_dwordx4 %20, %29, %30 offset:256 sc0 sc1\n\t"
                "global_load_dwordx4 %21, %29, %30 offset:320 sc0 sc1\n\t"
                "global_load_dwordx4 %22, %29, %30 offset:384 sc0 sc1\n\t"
                "global_load_dwordx4 %23, %29, %30 offset:448 sc0 sc1\n\t"
                "s_waitcnt vmcnt(0)"
                : "=&v"(xpr[0]), "=&v"(xpr[1]), "=&v"(xpr[2]), "=&v"(xpr[3]),
                  "=&v"(xpr[4]), "=&v"(xpr[5]), "=&v"(xpr[6]), "=&v"(xpr[7]),
                  "=&v"(xpr[8]), "=&v"(xpr[9]), "=&v"(xpr[10]), "=&v"(xpr[11]),
                  "=&v"(xpr[12]), "=&v"(xpr[13]), "=&v"(xpr[14]), "=&v"(xpr[15]),
                  "=&v"(afp[0]), "=&v"(afp[1]), "=&v"(afp[2]), "=&v"(afp[3]),
                  "=&v"(afp[4]), "=&v"(afp[5]), "=&v"(afp[6]), "=&v"(afp[7])
                : "v"(vxpr[0]), "v"(vxpr[1]), "v"(vxpr[2]), "v"(vxpr[3]),
                  "s"(xp), "v"(vafp), "s"(h_buf));
        }
        __builtin_amdgcn_sched_barrier(0);

        // peer-half MFMA
        #pragma unroll
        for (int i = 0; i < 8; ++i) {
            acc[0] = __builtin_amdgcn_mfma_f32_16x16x32_bf16(afp[i], bwp[0][i], acc[0], 0, 0, 0);
            acc[1] = __builtin_amdgcn_mfma_f32_16x16x32_bf16(afp[i], bwp[1][i], acc[1], 0, 0, 0);
            acc[2] = __builtin_amdgcn_mfma_f32_16x16x32_bf16(afp[i], bwp[2][i], acc[2], 0, 0, 0);
            acc[3] = __builtin_amdgcn_mfma_f32_16x16x32_bf16(afp[i], bwp[3][i], acc[3], 0, 0, 0);
        }

        // D/E: tanh epilogue; LDS own-half write; h stores + out stores + counted drain
        unsigned int pk[16];
        #pragma unroll
        for (int nt = 0; nt < 4; ++nt)
            #pragma unroll
            for (int r = 0; r < 4; ++r) {
                int i = nt * 4 + r;
                float pre = acc[nt][r] + xpr[i];
                float hv = tanh_fast(pre);
                if (t == T_ - 1)
                    h_final[(size_t)(erow_g + r) * H_ + jn0 + nt * 16 + lr] = hv;
                unsigned int mine = f2bf(hv);
                unsigned int oth = (unsigned int)__shfl_xor((int)mine, 1, 64);
                pk[i] = mine | (oth << 16);
            }
        if (!(lr & 1)) {
            unsigned int* lw = (unsigned int*)lds;
            #pragma unroll
            for (int nt = 0; nt < 4; ++nt)
                #pragma unroll
                for (int r = 0; r < 4; ++r)
                    lw[(erow_l + r) * 136 + cb + nt * 8] = pk[nt * 4 + r];
            unsigned int vh_p = vhs0 + ((unsigned)((t + 1) & 1) << 16);
            STORE_BUNDLE(pk, vh_p, vout);
        }
        // F: all h stores drained per-wave -> barrier -> release flag
        __syncthreads();
        if (tid == 0) {
            int nv = t + 1;
            asm volatile("global_store_dword %0, %1, %2 sc0 sc1"
                         :: "v"(fself), "v"(nv), "s"(flags) : "memory");
        }
        #pragma unroll
        for (int r = 0; r < 4; ++r) { vxpr[r] += H_ * 4; vout[r] += H_ * 2; }
    }
}

// ---------------- workspace layout (bytes) ----------------
#define OFF_XBF    ((size_t)0)
#define OFF_WIH0   ((size_t)16777216)
#define OFF_WHH0   ((size_t)17039360)
#define OFF_WIH1   ((size_t)17563648)
#define OFF_WHH1   ((size_t)18087936)
#define OFF_FCW    ((size_t)18612224)
#define OFF_XP     ((size_t)18874368)
#define OFF_OUTBF  ((size_t)85983232)
#define OFF_HBUF0  ((size_t)119537664)
#define OFF_HBUF1  ((size_t)119668736)
#define OFF_FLAGS  ((size_t)119799808)
#define WS_NEED    ((size_t)119803904)

extern "C" void kernel_launch(void* const* d_in, const int* in_sizes, int n_in,
                              void* d_out, int out_size, void* d_ws, size_t ws_size,
                              hipStream_t stream) {
    if (ws_size < WS_NEED) return;
    const float* x     = (const float*)d_in[0];
    const float* w_ih0 = (const float*)d_in[1];
    const float* w_hh0 = (const float*)d_in[2];
    const float* b_ih0 = (const float*)d_in[3];
    const float* b_hh0 = (const float*)d_in[4];
    const float* w_ih1 = (const float*)d_in[5];
    const float* w_hh1 = (const float*)d_in[6];
    const float* b_ih1 = (const float*)d_in[7];
    const float* b_hh1 = (const float*)d_in[8];
    const float* fc_w  = (const float*)d_in[9];
    const float* fc_b  = (const float*)d_in[10];

    char* ws = (char*)d_ws;
    unsigned short* x_bf     = (unsigned short*)(ws + OFF_XBF);
    unsigned short* w_ih0_bf = (unsigned short*)(ws + OFF_WIH0);
    unsigned short* w_hh0_bf = (unsigned short*)(ws + OFF_WHH0);
    unsigned short* w_ih1_bf = (unsigned short*)(ws + OFF_WIH1);
    unsigned short* w_hh1_bf = (unsigned short*)(ws + OFF_WHH1);
    unsigned short* fc_w_bf  = (unsigned short*)(ws + OFF_FCW);
    float*          xp       = (float*)(ws + OFF_XP);
    unsigned short* out_bf   = (unsigned short*)(ws + OFF_OUTBF);
    unsigned short* h_buf0   = (unsigned short*)(ws + OFF_HBUF0);
    unsigned short* h_buf1   = (unsigned short*)(ws + OFF_HBUF1);
    int*            flags0   = (int*)(ws + OFF_FLAGS);
    int*            flags1   = flags0 + NG * JW * FLAG_STRIDE;

    float* out  = (float*)d_out;
    float* hid0 = out + (size_t)B_ * T_ * O_;
    float* hid1 = hid0 + (size_t)B_ * H_;

    hipMemsetAsync(ws + OFF_HBUF0, 0, 131072 * 2 + 4096, stream);

    auto cvt = [&](const float* in, unsigned short* o, int n) {
        int n4 = n / 4;
        cvt_kernel<<<(n4 + 255) / 256, 256, 0, stream>>>(in, o, n4);
    };
    cvt(x,     x_bf,     B_ * T_ * I_);
    cvt(w_ih0, w_ih0_bf, H_ * I_);
    cvt(w_hh0, w_hh0_bf, H_ * H_);
    cvt(w_ih1, w_ih1_bf, H_ * H_);
    cvt(w_hh1, w_hh1_bf, H_ * H_);
    cvt(fc_w,  fc_w_bf,  O_ * H_);

    const int M = B_ * T_;

    gemm_kernel<<<dim3(M / 64, H_ / 64), 256, 0, stream>>>(
        x_bf, w_ih0_bf, b_ih0, b_hh0, xp, M, H_, I_);

    recur_kernel<<<NG * JW, 256, 0, stream>>>(xp, w_hh0_bf, out_bf, hid0, h_buf0, flags0);

    gemm_kernel<<<dim3(M / 64, H_ / 64), 256, 0, stream>>>(
        out_bf, w_ih1_bf, b_ih1, b_hh1, xp, M, H_, H_);

    recur_kernel<<<NG * JW, 256, 0, stream>>>(xp, w_hh1_bf, out_bf, hid1, h_buf1, flags1);

    gemm_kernel<<<dim3(M / 64, O_ / 64), 256, 0, stream>>>(
        out_bf, fc_w_bf, fc_b, nullptr, out, M, O_, H_);
}

// Round 7
// 3598.697 us; speedup vs baseline: 3.2692x; 1.2336x over previous
//
#include <hip/hip_runtime.h>

#define B_  64
#define T_  512
#define I_  256
#define H_  512
#define O_  256
#define JW  2
#define BS  16
#define NG  (B_ / BS)
#define SENT 0x7F7F7F7Fu
#define SLOT_BYTES 8192          // 16 rows x 256 cols bf16
#define BLK_SLOT_STRIDE 32768    // 4 slots per block

typedef __attribute__((ext_vector_type(8))) __bf16 bf16x8;
typedef __attribute__((ext_vector_type(4))) float f32x4;
typedef unsigned int u32x4 __attribute__((ext_vector_type(4)));

__device__ __forceinline__ unsigned short f2bf(float f) {
    unsigned int u = __float_as_uint(f);
    unsigned int r = (u + 0x7fffu + ((u >> 16) & 1u)) >> 16;
    return (unsigned short)r;
}

__device__ __forceinline__ float tanh_fast(float x) {
    float e = __expf(2.0f * x);
    float d = e + 1.0f;
    float r;
    asm("v_rcp_f32 %0, %1" : "=v"(r) : "v"(d));
    return 1.0f - 2.0f * r;
}

// ---------------- convert f32 -> bf16 ----------------
__global__ void cvt_kernel(const float* __restrict__ in, unsigned short* __restrict__ out, int n4) {
    int i = blockIdx.x * blockDim.x + threadIdx.x;
    if (i >= n4) return;
    float4 f = reinterpret_cast<const float4*>(in)[i];
    ushort4 o;
    o.x = f2bf(f.x); o.y = f2bf(f.y); o.z = f2bf(f.z); o.w = f2bf(f.w);
    reinterpret_cast<ushort4*>(out)[i] = o;
}

// ---------------- generic GEMM ----------------
__global__ __launch_bounds__(256) void gemm_kernel(
    const unsigned short* __restrict__ A,
    const unsigned short* __restrict__ Bw,
    const float* __restrict__ b0,
    const float* __restrict__ b1,
    float* __restrict__ C,
    int M, int N, int K)
{
    const int m0 = blockIdx.x * 64;
    const int n0 = blockIdx.y * 64;
    const int tid = threadIdx.x;
    const int wv = tid >> 6;
    const int l = tid & 63;
    const int lr = l & 15;
    const int lk = (l >> 4) * 8;
    const int arow = m0 + wv * 16 + lr;

    f32x4 acc[4] = {{0,0,0,0},{0,0,0,0},{0,0,0,0},{0,0,0,0}};
    const int nks = K / 32;
    for (int ks = 0; ks < nks; ++ks) {
        bf16x8 a = *reinterpret_cast<const bf16x8*>(A + (size_t)arow * K + ks * 32 + lk);
        #pragma unroll
        for (int nt = 0; nt < 4; ++nt) {
            bf16x8 b = *reinterpret_cast<const bf16x8*>(Bw + (size_t)(n0 + nt * 16 + lr) * K + ks * 32 + lk);
            acc[nt] = __builtin_amdgcn_mfma_f32_16x16x32_bf16(a, b, acc[nt], 0, 0, 0);
        }
    }
    #pragma unroll
    for (int nt = 0; nt < 4; ++nt) {
        #pragma unroll
        for (int r = 0; r < 4; ++r) {
            int row = m0 + wv * 16 + (l >> 4) * 4 + r;
            int col = n0 + nt * 16 + lr;
            float v = acc[nt][r];
            if (b0) v += b0[col];
            if (b1) v += b1[col];
            C[(size_t)row * N + col] = v;
        }
    }
}

// ---------------- recurrence (sentinel / data-as-flag protocol) ----------------
#define LDW8(ARR, BASE) \
    asm volatile( \
        "global_load_dwordx4 %0, %8, %9 offset:0\n\t" \
        "global_load_dwordx4 %1, %8, %9 offset:64\n\t" \
        "global_load_dwordx4 %2, %8, %9 offset:128\n\t" \
        "global_load_dwordx4 %3, %8, %9 offset:192\n\t" \
        "global_load_dwordx4 %4, %8, %9 offset:256\n\t" \
        "global_load_dwordx4 %5, %8, %9 offset:320\n\t" \
        "global_load_dwordx4 %6, %8, %9 offset:384\n\t" \
        "global_load_dwordx4 %7, %8, %9 offset:448\n\t" \
        "s_waitcnt vmcnt(0)" \
        : "=&v"(ARR[0]), "=&v"(ARR[1]), "=&v"(ARR[2]), "=&v"(ARR[3]), \
          "=&v"(ARR[4]), "=&v"(ARR[5]), "=&v"(ARR[6]), "=&v"(ARR[7]) \
        : "v"(BASE), "s"(w))

// 16 slot stores (MALL, sc0 sc1) + 16 out stores (HBM) -- fire and forget, NO wait
#define STORE_SLOT_OUT(PK, VSLW, VOUT) \
    asm volatile( \
        "global_store_dword %16, %0, %21 sc0 sc1\n\t" \
        "global_store_dword %16, %1, %21 offset:512 sc0 sc1\n\t" \
        "global_store_dword %16, %2, %21 offset:1024 sc0 sc1\n\t" \
        "global_store_dword %16, %3, %21 offset:1536 sc0 sc1\n\t" \
        "global_store_dword %16, %4, %21 offset:32 sc0 sc1\n\t" \
        "global_store_dword %16, %5, %21 offset:544 sc0 sc1\n\t" \
        "global_store_dword %16, %6, %21 offset:1056 sc0 sc1\n\t" \
        "global_store_dword %16, %7, %21 offset:1568 sc0 sc1\n\t" \
        "global_store_dword %16, %8, %21 offset:64 sc0 sc1\n\t" \
        "global_store_dword %16, %9, %21 offset:576 sc0 sc1\n\t" \
        "global_store_dword %16, %10, %21 offset:1088 sc0 sc1\n\t" \
        "global_store_dword %16, %11, %21 offset:1600 sc0 sc1\n\t" \
        "global_store_dword %16, %12, %21 offset:96 sc0 sc1\n\t" \
        "global_store_dword %16, %13, %21 offset:608 sc0 sc1\n\t" \
        "global_store_dword %16, %14, %21 offset:1120 sc0 sc1\n\t" \
        "global_store_dword %16, %15, %21 offset:1632 sc0 sc1\n\t" \
        "global_store_dword %17, %0, %22\n\t" \
        "global_store_dword %18, %1, %22\n\t" \
        "global_store_dword %19, %2, %22\n\t" \
        "global_store_dword %20, %3, %22\n\t" \
        "global_store_dword %17, %4, %22 offset:32\n\t" \
        "global_store_dword %18, %5, %22 offset:32\n\t" \
        "global_store_dword %19, %6, %22 offset:32\n\t" \
        "global_store_dword %20, %7, %22 offset:32\n\t" \
        "global_store_dword %17, %8, %22 offset:64\n\t" \
        "global_store_dword %18, %9, %22 offset:64\n\t" \
        "global_store_dword %19, %10, %22 offset:64\n\t" \
        "global_store_dword %20, %11, %22 offset:64\n\t" \
        "global_store_dword %17, %12, %22 offset:96\n\t" \
        "global_store_dword %18, %13, %22 offset:96\n\t" \
        "global_store_dword %19, %14, %22 offset:96\n\t" \
        "global_store_dword %20, %15, %22 offset:96" \
        :: "v"(PK[0]), "v"(PK[1]), "v"(PK[2]), "v"(PK[3]), \
           "v"(PK[4]), "v"(PK[5]), "v"(PK[6]), "v"(PK[7]), \
           "v"(PK[8]), "v"(PK[9]), "v"(PK[10]), "v"(PK[11]), \
           "v"(PK[12]), "v"(PK[13]), "v"(PK[14]), "v"(PK[15]), \
           "v"(VSLW), "v"(VOUT[0]), "v"(VOUT[1]), "v"(VOUT[2]), "v"(VOUT[3]), \
           "s"(slots), "s"(out_bf) \
        : "memory")

__global__ __launch_bounds__(256, 1) void recur_kernel(
    const float* __restrict__ xp,          // [B][T][H] f32 preactivation
    const unsigned short* __restrict__ w,  // [H][H] bf16
    unsigned short* __restrict__ out_bf,   // [B][T][H] bf16
    float* __restrict__ h_final,           // [B][H] f32
    unsigned short* __restrict__ slots)    // [8 blocks][4 slots][16][256] bf16, 0x7F-filled
{
    __shared__ __align__(16) unsigned short lds[16 * 280];   // own-half h, 560B row stride

    const int bid = blockIdx.x;
    const int g   = bid >> 1;
    const int jw  = bid & 1;
    const int pjw = jw ^ 1;
    const int b0  = g * BS;
    const int tid = threadIdx.x;
    const int wv  = tid >> 6;
    const int l   = tid & 63;
    const int lr  = l & 15;
    const int lk  = (l >> 4) * 8;
    const int jn0 = jw * 256 + wv * 64;
    const int erow_l = (l >> 4) * 4;
    const int erow_g = b0 + erow_l;

    // ---- weights -> registers, once ----
    bf16x8 bwo[4][8], bwp[4][8];
    #pragma unroll
    for (int nt = 0; nt < 4; ++nt) {
        unsigned int vo = (unsigned)((jn0 + nt * 16 + lr) * (H_ * 2) + jw  * 512 + lk * 2);
        unsigned int vp = (unsigned)((jn0 + nt * 16 + lr) * (H_ * 2) + pjw * 512 + lk * 2);
        LDW8(bwo[nt], vo);
        LDW8(bwp[nt], vp);
    }

    // ---- addresses ----
    unsigned int vxpr[4], vout[4];
    #pragma unroll
    for (int r = 0; r < 4; ++r) {
        vxpr[r] = (unsigned)((((erow_g + r) * T_) * H_ + jn0 + lr) * 4);
        vout[r] = (unsigned)(((erow_g + r) * T_) * H_ * 2 + (jn0 + lr) * 2);
    }
    const unsigned int slot_wr_b = (unsigned)(bid * BLK_SLOT_STRIDE);
    const unsigned int slot_rd_b = (unsigned)((bid ^ 1) * BLK_SLOT_STRIDE);
    const unsigned int vslr_base = slot_rd_b + (unsigned)(lr * 512 + lk * 2);   // peer A-frag
    const unsigned int vslw_base = slot_wr_b + (unsigned)(erow_l * 512 + (wv * 64 + lr) * 2);
    const unsigned int vsent_base = slot_rd_b + (unsigned)(wv * 2048 + l * 16); // re-sentinel
    const u32x4 sentq = {SENT, SENT, SENT, SENT};

    // ================= t = 0 peel: h1 = tanh(xp[0]) =================
    {
        float xpr[16];
        asm volatile(
            "global_load_dword %0, %16, %20\n\t"
            "global_load_dword %1, %17, %20\n\t"
            "global_load_dword %2, %18, %20\n\t"
            "global_load_dword %3, %19, %20\n\t"
            "global_load_dword %4, %16, %20 offset:64\n\t"
            "global_load_dword %5, %17, %20 offset:64\n\t"
            "global_load_dword %6, %18, %20 offset:64\n\t"
            "global_load_dword %7, %19, %20 offset:64\n\t"
            "global_load_dword %8, %16, %20 offset:128\n\t"
            "global_load_dword %9, %17, %20 offset:128\n\t"
            "global_load_dword %10, %18, %20 offset:128\n\t"
            "global_load_dword %11, %19, %20 offset:128\n\t"
            "global_load_dword %12, %16, %20 offset:192\n\t"
            "global_load_dword %13, %17, %20 offset:192\n\t"
            "global_load_dword %14, %18, %20 offset:192\n\t"
            "global_load_dword %15, %19, %20 offset:192\n\t"
            "s_waitcnt vmcnt(0)"
            : "=&v"(xpr[0]), "=&v"(xpr[1]), "=&v"(xpr[2]), "=&v"(xpr[3]),
              "=&v"(xpr[4]), "=&v"(xpr[5]), "=&v"(xpr[6]), "=&v"(xpr[7]),
              "=&v"(xpr[8]), "=&v"(xpr[9]), "=&v"(xpr[10]), "=&v"(xpr[11]),
              "=&v"(xpr[12]), "=&v"(xpr[13]), "=&v"(xpr[14]), "=&v"(xpr[15])
            : "v"(vxpr[0]), "v"(vxpr[1]), "v"(vxpr[2]), "v"(vxpr[3]), "s"(xp));

        unsigned int pk[16];
        #pragma unroll
        for (int nt = 0; nt < 4; ++nt)
            #pragma unroll
            for (int r = 0; r < 4; ++r) {
                int i = nt * 4 + r;
                float hv = tanh_fast(xpr[i]);
                unsigned int mine = f2bf(hv);
                unsigned int oth = (unsigned int)__shfl_xor((int)mine, 1, 64);
                pk[i] = mine | (oth << 16);
            }
        if (!(lr & 1)) {
            unsigned int* lw = (unsigned int*)lds;
            const int cb = wv * 32 + (lr >> 1);
            #pragma unroll
            for (int nt = 0; nt < 4; ++nt)
                #pragma unroll
                for (int r = 0; r < 4; ++r)
                    lw[(erow_l + r) * 140 + cb + nt * 8] = pk[nt * 4 + r];
            unsigned int vslw = vslw_base + 1u * SLOT_BYTES;   // slot (0+1)&3 = 1
            STORE_SLOT_OUT(pk, vslw, vout);
        }
        __syncthreads();
        #pragma unroll
        for (int r = 0; r < 4; ++r) { vxpr[r] += H_ * 4; vout[r] += H_ * 2; }
    }

    // ================= main loop t = 1..T-1 =================
    for (int t = 1; t < T_; ++t) {
        // A: own-half MFMA from LDS
        f32x4 acc[4] = {{0,0,0,0},{0,0,0,0},{0,0,0,0},{0,0,0,0}};
        {
            bf16x8 afo[8];
            const unsigned short* lrb = lds + lr * 280 + lk;
            #pragma unroll
            for (int i = 0; i < 8; ++i)
                afo[i] = *reinterpret_cast<const bf16x8*>(lrb + i * 32);
            #pragma unroll
            for (int i = 0; i < 8; ++i) {
                acc[0] = __builtin_amdgcn_mfma_f32_16x16x32_bf16(afo[i], bwo[0][i], acc[0], 0, 0, 0);
                acc[1] = __builtin_amdgcn_mfma_f32_16x16x32_bf16(afo[i], bwo[1][i], acc[1], 0, 0, 0);
                acc[2] = __builtin_amdgcn_mfma_f32_16x16x32_bf16(afo[i], bwo[2][i], acc[2], 0, 0, 0);
                acc[3] = __builtin_amdgcn_mfma_f32_16x16x32_bf16(afo[i], bwo[3][i], acc[3], 0, 0, 0);
            }
        }
        __builtin_amdgcn_sched_barrier(0);

        // B: poll peer slot (data-as-flag). First bundle also loads xp (latency hidden).
        const unsigned int vslr = vslr_base + (unsigned)(t & 3) * SLOT_BYTES;
        float xpr[16];
        u32x4 afp[8];
        asm volatile(
            "global_load_dword %0, %24, %28\n\t"
            "global_load_dword %1, %25, %28\n\t"
            "global_load_dword %2, %26, %28\n\t"
            "global_load_dword %3, %27, %28\n\t"
            "global_load_dword %4, %24, %28 offset:64\n\t"
            "global_load_dword %5, %25, %28 offset:64\n\t"
            "global_load_dword %6, %26, %28 offset:64\n\t"
            "global_load_dword %7, %27, %28 offset:64\n\t"
            "global_load_dword %8, %24, %28 offset:128\n\t"
            "global_load_dword %9, %25, %28 offset:128\n\t"
            "global_load_dword %10, %26, %28 offset:128\n\t"
            "global_load_dword %11, %27, %28 offset:128\n\t"
            "global_load_dword %12, %24, %28 offset:192\n\t"
            "global_load_dword %13, %25, %28 offset:192\n\t"
            "global_load_dword %14, %26, %28 offset:192\n\t"
            "global_load_dword %15, %27, %28 offset:192\n\t"
            "global_load_dwordx4 %16, %29, %30 sc0 sc1\n\t"
            "global_load_dwordx4 %17, %29, %30 offset:64 sc0 sc1\n\t"
            "global_load_dwordx4 %18, %29, %30 offset:128 sc0 sc1\n\t"
            "global_load_dwordx4 %19, %29, %30 offset:192 sc0 sc1\n\t"
            "global_load_dwordx4 %20, %29, %30 offset:256 sc0 sc1\n\t"
            "global_load_dwordx4 %21, %29, %30 offset:320 sc0 sc1\n\t"
            "global_load_dwordx4 %22, %29, %30 offset:384 sc0 sc1\n\t"
            "global_load_dwordx4 %23, %29, %30 offset:448 sc0 sc1\n\t"
            "s_waitcnt vmcnt(0)"
            : "=&v"(xpr[0]), "=&v"(xpr[1]), "=&v"(xpr[2]), "=&v"(xpr[3]),
              "=&v"(xpr[4]), "=&v"(xpr[5]), "=&v"(xpr[6]), "=&v"(xpr[7]),
              "=&v"(xpr[8]), "=&v"(xpr[9]), "=&v"(xpr[10]), "=&v"(xpr[11]),
              "=&v"(xpr[12]), "=&v"(xpr[13]), "=&v"(xpr[14]), "=&v"(xpr[15]),
              "=&v"(afp[0]), "=&v"(afp[1]), "=&v"(afp[2]), "=&v"(afp[3]),
              "=&v"(afp[4]), "=&v"(afp[5]), "=&v"(afp[6]), "=&v"(afp[7])
            : "v"(vxpr[0]), "v"(vxpr[1]), "v"(vxpr[2]), "v"(vxpr[3]),
              "s"(xp), "v"(vslr), "s"(slots));

        int bad = 0;
        #pragma unroll
        for (int i = 0; i < 8; ++i)
            #pragma unroll
            for (int j = 0; j < 4; ++j)
                bad |= (afp[i][j] == SENT);
        while (__any(bad)) {
            asm volatile(
                "global_load_dwordx4 %0, %8, %9 sc0 sc1\n\t"
                "global_load_dwordx4 %1, %8, %9 offset:64 sc0 sc1\n\t"
                "global_load_dwordx4 %2, %8, %9 offset:128 sc0 sc1\n\t"
                "global_load_dwordx4 %3, %8, %9 offset:192 sc0 sc1\n\t"
                "global_load_dwordx4 %4, %8, %9 offset:256 sc0 sc1\n\t"
                "global_load_dwordx4 %5, %8, %9 offset:320 sc0 sc1\n\t"
                "global_load_dwordx4 %6, %8, %9 offset:384 sc0 sc1\n\t"
                "global_load_dwordx4 %7, %8, %9 offset:448 sc0 sc1\n\t"
                "s_waitcnt vmcnt(0)"
                : "=&v"(afp[0]), "=&v"(afp[1]), "=&v"(afp[2]), "=&v"(afp[3]),
                  "=&v"(afp[4]), "=&v"(afp[5]), "=&v"(afp[6]), "=&v"(afp[7])
                : "v"(vslr), "s"(slots));
            bad = 0;
            #pragma unroll
            for (int i = 0; i < 8; ++i)
                #pragma unroll
                for (int j = 0; j < 4; ++j)
                    bad |= (afp[i][j] == SENT);
        }
        __builtin_amdgcn_sched_barrier(0);

        // C: peer-half MFMA
        #pragma unroll
        for (int i = 0; i < 8; ++i) {
            bf16x8 a = __builtin_bit_cast(bf16x8, afp[i]);
            acc[0] = __builtin_amdgcn_mfma_f32_16x16x32_bf16(a, bwp[0][i], acc[0], 0, 0, 0);
            acc[1] = __builtin_amdgcn_mfma_f32_16x16x32_bf16(a, bwp[1][i], acc[1], 0, 0, 0);
            acc[2] = __builtin_amdgcn_mfma_f32_16x16x32_bf16(a, bwp[2][i], acc[2], 0, 0, 0);
            acc[3] = __builtin_amdgcn_mfma_f32_16x16x32_bf16(a, bwp[3][i], acc[3], 0, 0, 0);
        }

        // D: epilogue
        unsigned int pk[16];
        #pragma unroll
        for (int nt = 0; nt < 4; ++nt)
            #pragma unroll
            for (int r = 0; r < 4; ++r) {
                int i = nt * 4 + r;
                float pre = acc[nt][r] + xpr[i];
                float hv = tanh_fast(pre);
                if (t == T_ - 1)
                    h_final[(size_t)(erow_g + r) * H_ + jn0 + nt * 16 + lr] = hv;
                unsigned int mine = f2bf(hv);
                unsigned int oth = (unsigned int)__shfl_xor((int)mine, 1, 64);
                pk[i] = mine | (oth << 16);
            }
        if (!(lr & 1)) {
            unsigned int* lw = (unsigned int*)lds;
            const int cb = wv * 32 + (lr >> 1);
            #pragma unroll
            for (int nt = 0; nt < 4; ++nt)
                #pragma unroll
                for (int r = 0; r < 4; ++r)
                    lw[(erow_l + r) * 140 + cb + nt * 8] = pk[nt * 4 + r];
            unsigned int vslw = vslw_base + (unsigned)((t + 1) & 3) * SLOT_BYTES;
            STORE_SLOT_OUT(pk, vslw, vout);   // fire and forget
        }

        // E: step barrier (all waves consumed slot + LDS ready)
        __syncthreads();

        // F: re-sentinel the consumed slot (each wave its quarter, fire and forget)
        {
            unsigned int vs = vsent_base + (unsigned)(t & 3) * SLOT_BYTES;
            asm volatile(
                "global_store_dwordx4 %0, %1, %2 sc0 sc1\n\t"
                "global_store_dwordx4 %0, %1, %2 offset:1024 sc0 sc1"
                :: "v"(vs), "v"(sentq), "s"(slots) : "memory");
        }
        #pragma unroll
        for (int r = 0; r < 4; ++r) { vxpr[r] += H_ * 4; vout[r] += H_ * 2; }
    }
}

// ---------------- workspace layout (bytes) ----------------
#define OFF_XBF    ((size_t)0)
#define OFF_WIH0   ((size_t)16777216)
#define OFF_WHH0   ((size_t)17039360)
#define OFF_WIH1   ((size_t)17563648)
#define OFF_WHH1   ((size_t)18087936)
#define OFF_FCW    ((size_t)18612224)
#define OFF_XP     ((size_t)18874368)
#define OFF_OUTBF  ((size_t)85983232)
#define OFF_SLOTS  ((size_t)119537664)   // 8 blocks x 4 slots x 8192 B = 262144
#define WS_NEED    ((size_t)119799808)

extern "C" void kernel_launch(void* const* d_in, const int* in_sizes, int n_in,
                              void* d_out, int out_size, void* d_ws, size_t ws_size,
                              hipStream_t stream) {
    if (ws_size < WS_NEED) return;
    const float* x     = (const float*)d_in[0];
    const float* w_ih0 = (const float*)d_in[1];
    const float* w_hh0 = (const float*)d_in[2];
    const float* b_ih0 = (const float*)d_in[3];
    const float* b_hh0 = (const float*)d_in[4];
    const float* w_ih1 = (const float*)d_in[5];
    const float* w_hh1 = (const float*)d_in[6];
    const float* b_ih1 = (const float*)d_in[7];
    const float* b_hh1 = (const float*)d_in[8];
    const float* fc_w  = (const float*)d_in[9];
    const float* fc_b  = (const float*)d_in[10];

    char* ws = (char*)d_ws;
    unsigned short* x_bf     = (unsigned short*)(ws + OFF_XBF);
    unsigned short* w_ih0_bf = (unsigned short*)(ws + OFF_WIH0);
    unsigned short* w_hh0_bf = (unsigned short*)(ws + OFF_WHH0);
    unsigned short* w_ih1_bf = (unsigned short*)(ws + OFF_WIH1);
    unsigned short* w_hh1_bf = (unsigned short*)(ws + OFF_WHH1);
    unsigned short* fc_w_bf  = (unsigned short*)(ws + OFF_FCW);
    float*          xp       = (float*)(ws + OFF_XP);
    unsigned short* out_bf   = (unsigned short*)(ws + OFF_OUTBF);
    unsigned short* slots    = (unsigned short*)(ws + OFF_SLOTS);

    float* out  = (float*)d_out;
    float* hid0 = out + (size_t)B_ * T_ * O_;
    float* hid1 = hid0 + (size_t)B_ * H_;

    // sentinel-fill slots for layer 0
    hipMemsetAsync(ws + OFF_SLOTS, 0x7F, 262144, stream);

    auto cvt = [&](const float* in, unsigned short* o, int n) {
        int n4 = n / 4;
        cvt_kernel<<<(n4 + 255) / 256, 256, 0, stream>>>(in, o, n4);
    };
    cvt(x,     x_bf,     B_ * T_ * I_);
    cvt(w_ih0, w_ih0_bf, H_ * I_);
    cvt(w_hh0, w_hh0_bf, H_ * H_);
    cvt(w_ih1, w_ih1_bf, H_ * H_);
    cvt(w_hh1, w_hh1_bf, H_ * H_);
    cvt(fc_w,  fc_w_bf,  O_ * H_);

    const int M = B_ * T_;

    gemm_kernel<<<dim3(M / 64, H_ / 64), 256, 0, stream>>>(
        x_bf, w_ih0_bf, b_ih0, b_hh0, xp, M, H_, I_);

    recur_kernel<<<NG * JW, 256, 0, stream>>>(xp, w_hh0_bf, out_bf, hid0, slots);

    gemm_kernel<<<dim3(M / 64, H_ / 64), 256, 0, stream>>>(
        out_bf, w_ih1_bf, b_ih1, b_hh1, xp, M, H_, H_);

    // re-sentinel slots for layer 1 (stream-ordered after layer-0 recur)
    hipMemsetAsync(ws + OFF_SLOTS, 0x7F, 262144, stream);

    recur_kernel<<<NG * JW, 256, 0, stream>>>(xp, w_hh1_bf, out_bf, hid1, slots);

    gemm_kernel<<<dim3(M / 64, O_ / 64), 256, 0, stream>>>(
        out_bf, fc_w_bf, fc_b, nullptr, out, M, O_, H_);
}